// Round 12
// baseline (563.037 us; speedup 1.0000x reference)
//
#include <hip/hip_runtime.h>
#include <hip/hip_bf16.h>
#include <cstdint>

#define NNODES 50000
#define NEDGES 800000
constexpr float SLOPE = 0.2f;

__device__ __forceinline__ float leakyf(float x){ return x > 0.f ? x : SLOPE * x; }
__device__ __forceinline__ float eluf(float x){ return x > 0.f ? x : expm1f(x); }

// ---------------- CSR build (by dst) ----------------
__global__ void hist_kernel(const int* __restrict__ dst, int* __restrict__ deg, int e){
  int i = blockIdx.x * 256 + threadIdx.x;
  if (i < e) atomicAdd(&deg[dst[i]], 1);
}

__global__ __launch_bounds__(256) void scan1_kernel(const int* __restrict__ deg,
    int* __restrict__ pre, int* __restrict__ bsum, int n){
  __shared__ int s[256];
  int t = threadIdx.x;
  int i = blockIdx.x * 256 + t;
  int v = (i < n) ? deg[i] : 0;
  s[t] = v;
  __syncthreads();
  #pragma unroll
  for (int off = 1; off < 256; off <<= 1){
    int x = (t >= off) ? s[t - off] : 0;
    __syncthreads();
    s[t] += x;
    __syncthreads();
  }
  if (i < n) pre[i] = s[t] - v;
  if (t == 255) bsum[blockIdx.x] = s[255];
}

__global__ __launch_bounds__(256) void scan2_kernel(int* __restrict__ bsum, int nb){
  __shared__ int s[256];
  int t = threadIdx.x;
  int v = (t < nb) ? bsum[t] : 0;
  s[t] = v;
  __syncthreads();
  #pragma unroll
  for (int off = 1; off < 256; off <<= 1){
    int x = (t >= off) ? s[t - off] : 0;
    __syncthreads();
    s[t] += x;
    __syncthreads();
  }
  if (t < nb) bsum[t] = s[t] - v;
}

__global__ __launch_bounds__(256) void scan3_kernel(const int* __restrict__ pre,
    const int* __restrict__ bsum, int* __restrict__ row, int* __restrict__ cur,
    int n, int etot){
  int i = blockIdx.x * 256 + threadIdx.x;
  if (i < n){
    int r = pre[i] + bsum[i >> 8];
    row[i] = r; cur[i] = r;
  }
  if (i == n) row[n] = etot;
}

__global__ void scatter_kernel(const int* __restrict__ src, const int* __restrict__ dst,
    int* __restrict__ cur, int* __restrict__ ssrc, int* __restrict__ sdst, int e){
  int i = blockIdx.x * 256 + threadIdx.x;
  if (i < e){
    int d = dst[i];
    int pos = atomicAdd(&cur[d], 1);
    ssrc[pos] = src[i];
    sdst[pos] = d;
  }
}

// ---------------- f32 tiled GEMM 64x64 (A-tile transposed in LDS: b128 fragment reads) ----------------
template<int K, bool ACC>
__global__ __launch_bounds__(256) void gemm_kernel(const float* __restrict__ A,
    const float* __restrict__ B, float* __restrict__ C, int n_rows, int n_cols){
  __shared__ float Ast[64][68];   // transposed: Ast[k][r]
  __shared__ float Bs[64][64];
  int tx = threadIdx.x & 15, ty = threadIdx.x >> 4;
  int row0 = blockIdx.x * 64, col0 = blockIdx.y * 64;
  float acc[4][4] = {};
  for (int k0 = 0; k0 < K; k0 += 64){
    for (int v = threadIdx.x; v < 1024; v += 256){
      int r = v >> 4, c = (v & 15) << 2;
      float4 val = make_float4(0.f, 0.f, 0.f, 0.f);
      int gr = row0 + r;
      if (gr < n_rows) val = *reinterpret_cast<const float4*>(&A[(size_t)gr * K + k0 + c]);
      Ast[c + 0][r] = val.x;
      Ast[c + 1][r] = val.y;
      Ast[c + 2][r] = val.z;
      Ast[c + 3][r] = val.w;
    }
    for (int v = threadIdx.x; v < 1024; v += 256){
      int r = v >> 4, c = (v & 15) << 2;
      *reinterpret_cast<float4*>(&Bs[r][c]) =
        *reinterpret_cast<const float4*>(&B[(size_t)(k0 + r) * n_cols + col0 + c]);
    }
    __syncthreads();
    #pragma unroll 8
    for (int k = 0; k < 64; ++k){
      float4 av = *reinterpret_cast<const float4*>(&Ast[k][ty << 2]);
      float4 bv = *reinterpret_cast<const float4*>(&Bs[k][tx << 2]);
      float a[4] = {av.x, av.y, av.z, av.w};
      float b[4] = {bv.x, bv.y, bv.z, bv.w};
      #pragma unroll
      for (int i = 0; i < 4; ++i)
        #pragma unroll
        for (int j = 0; j < 4; ++j)
          acc[i][j] += a[i] * b[j];
    }
    __syncthreads();
  }
  #pragma unroll
  for (int i = 0; i < 4; ++i){
    int gr = row0 + ty * 4 + i;
    if (gr < n_rows){
      float* cp = &C[(size_t)gr * n_cols + col0 + tx * 4];
      float4 v = make_float4(acc[i][0], acc[i][1], acc[i][2], acc[i][3]);
      if constexpr (ACC){
        float4 o = *reinterpret_cast<const float4*>(cp);
        v.x += o.x; v.y += o.y; v.z += o.z; v.w += o.w;
      }
      *reinterpret_cast<float4*>(cp) = v;
    }
  }
}

// ---------------- f32 tiled GEMM 32x64: for low-block-count deep-K cases (K=768) ----------------
template<int K, bool ACC>
__global__ __launch_bounds__(256) void gemm32_kernel(const float* __restrict__ A,
    const float* __restrict__ B, float* __restrict__ C, int n_rows, int n_cols){
  __shared__ float Ast[64][36];   // transposed A panel: Ast[k][r], 32 rows, stride 144B
  __shared__ float Bs[64][64];
  int tx = threadIdx.x & 15, ty = threadIdx.x >> 4;   // tx: 16 col groups x4; ty: 16 row groups x2
  int row0 = blockIdx.x * 32, col0 = blockIdx.y * 64;
  float acc[2][4] = {};
  for (int k0 = 0; k0 < K; k0 += 64){
    for (int v = threadIdx.x; v < 512; v += 256){
      int r = v >> 4, c = (v & 15) << 2;
      float4 val = make_float4(0.f, 0.f, 0.f, 0.f);
      int gr = row0 + r;
      if (gr < n_rows) val = *reinterpret_cast<const float4*>(&A[(size_t)gr * K + k0 + c]);
      Ast[c + 0][r] = val.x;
      Ast[c + 1][r] = val.y;
      Ast[c + 2][r] = val.z;
      Ast[c + 3][r] = val.w;
    }
    for (int v = threadIdx.x; v < 1024; v += 256){
      int r = v >> 4, c = (v & 15) << 2;
      *reinterpret_cast<float4*>(&Bs[r][c]) =
        *reinterpret_cast<const float4*>(&B[(size_t)(k0 + r) * n_cols + col0 + c]);
    }
    __syncthreads();
    #pragma unroll 8
    for (int k = 0; k < 64; ++k){
      float2 av = *reinterpret_cast<const float2*>(&Ast[k][ty << 1]);
      float4 bv = *reinterpret_cast<const float4*>(&Bs[k][tx << 2]);
      float a[2] = {av.x, av.y};
      float b[4] = {bv.x, bv.y, bv.z, bv.w};
      #pragma unroll
      for (int i = 0; i < 2; ++i)
        #pragma unroll
        for (int j = 0; j < 4; ++j)
          acc[i][j] += a[i] * b[j];
    }
    __syncthreads();
  }
  #pragma unroll
  for (int i = 0; i < 2; ++i){
    int gr = row0 + ty * 2 + i;
    if (gr < n_rows){
      float* cp = &C[(size_t)gr * n_cols + col0 + tx * 4];
      float4 v = make_float4(acc[i][0], acc[i][1], acc[i][2], acc[i][3]);
      if constexpr (ACC){
        float4 o = *reinterpret_cast<const float4*>(cp);
        v.x += o.x; v.y += o.y; v.z += o.z; v.w += o.w;
      }
      *reinterpret_cast<float4*>(cp) = v;
    }
  }
}

// ---------------- combined weight prep: wvec0 | wvec2 | wresmean | w2r in one dispatch ----------------
__global__ __launch_bounds__(256) void prep_kernel(const float* __restrict__ W0,
    const float* __restrict__ al0, const float* __restrict__ ar0,
    const float* __restrict__ W2, const float* __restrict__ al2, const float* __restrict__ ar2,
    const float* __restrict__ Wres,
    float* __restrict__ wl0, float* __restrict__ wr0,
    float* __restrict__ wl2, float* __restrict__ wr2,
    float* __restrict__ wm, float* __restrict__ W2r){
  int b = blockIdx.x, t = threadIdx.x;
  if (b == 0){
    int h = t >> 6, k = t & 63;
    const float* wrow = W0 + (size_t)k * 128 + h * 32;
    const float* a = al0 + h * 32;
    const float* r = ar0 + h * 32;
    float sl = 0.f, sr = 0.f;
    #pragma unroll
    for (int d = 0; d < 32; ++d){ float wv = wrow[d]; sl += wv * a[d]; sr += wv * r[d]; }
    wl0[t] = sl; wr0[t] = sr;
  } else if (b < 4){
    int idx = (b - 1) * 256 + t;
    int h = idx / 128, k = idx - h * 128;
    const float* wrow = W2 + (size_t)k * 384 + h * 64;
    const float* a = al2 + h * 64;
    const float* r = ar2 + h * 64;
    float sl = 0.f, sr = 0.f;
    #pragma unroll
    for (int d = 0; d < 64; ++d){ float wv = wrow[d]; sl += wv * a[d]; sr += wv * r[d]; }
    wl2[idx] = sl; wr2[idx] = sr;
  } else if (b < 36){
    int i = (b - 4) * 256 + t;
    int k = i >> 6, c = i & 63;
    float s = 0.f;
    #pragma unroll
    for (int h = 0; h < 6; ++h) s += Wres[k * 384 + h * 64 + c];
    wm[i] = s * (1.f / 6.f);
  } else {
    int i = (b - 36) * 256 + t;
    int hk = i >> 6, c = i & 63;
    int h = hk >> 7, k = hk & 127;
    W2r[i] = W2[(size_t)k * 384 + h * 64 + c];
  }
}

// ---------------- node-parallel el/er from raw features ----------------
template<int H, int K>
__global__ __launch_bounds__(256) void elrn_kernel(const float* __restrict__ x,
    const float* __restrict__ wl, const float* __restrict__ wr,
    float* __restrict__ el, float* __restrict__ er){
  __shared__ float wls[H * K], wrs[H * K];
  for (int v = threadIdx.x; v < H * K; v += 256){ wls[v] = wl[v]; wrs[v] = wr[v]; }
  __syncthreads();
  int n = blockIdx.x * 256 + threadIdx.x;
  if (n >= NNODES) return;
  const float* xr = x + (size_t)n * K;
  float accl[H] = {}, accr[H] = {};
  for (int k = 0; k < K; k += 4){
    float4 xv = *reinterpret_cast<const float4*>(xr + k);
    #pragma unroll
    for (int h = 0; h < H; ++h){
      const float* a = &wls[h * K + k];
      const float* b = &wrs[h * K + k];
      accl[h] += xv.x * a[0] + xv.y * a[1] + xv.z * a[2] + xv.w * a[3];
      accr[h] += xv.x * b[0] + xv.y * b[1] + xv.z * b[2] + xv.w * b[3];
    }
  }
  #pragma unroll
  for (int h = 0; h < H; ++h){ el[n * H + h] = accl[h]; er[n * H + h] = accr[h]; }
}

// ---------------- node-parallel el/er for layer 1 ----------------
__global__ __launch_bounds__(256) void elr1_kernel(const float* __restrict__ feat,
    const float* __restrict__ al, const float* __restrict__ ar,
    float* __restrict__ el, float* __restrict__ er){
  __shared__ float als[128], ars[128];
  if (threadIdx.x < 128){ als[threadIdx.x] = al[threadIdx.x]; ars[threadIdx.x] = ar[threadIdx.x]; }
  __syncthreads();
  int n = blockIdx.x * 256 + threadIdx.x;
  if (n >= NNODES) return;
  const float* f = feat + (size_t)n * 128;
  float el4[4], er4[4];
  #pragma unroll
  for (int h = 0; h < 4; ++h){
    float sl = 0.f, sr = 0.f;
    #pragma unroll
    for (int d = 0; d < 32; d += 4){
      float4 fv = *reinterpret_cast<const float4*>(f + h * 32 + d);
      const float* a = &als[h * 32 + d];
      const float* b = &ars[h * 32 + d];
      sl += fv.x * a[0] + fv.y * a[1] + fv.z * a[2] + fv.w * a[3];
      sr += fv.x * b[0] + fv.y * b[1] + fv.z * b[2] + fv.w * b[3];
    }
    el4[h] = sl; er4[h] = sr;
  }
  *reinterpret_cast<float4*>(&el[n * 4]) = make_float4(el4[0], el4[1], el4[2], el4[3]);
  *reinterpret_cast<float4*>(&er[n * 4]) = make_float4(er4[0], er4[1], er4[2], er4[3]);
}

// ---------------- ex = exp(leaky(el[src]+er[dst])) ----------------
template<int H>
__global__ void ex_kernel(const float* __restrict__ el, const float* __restrict__ er,
    const int* __restrict__ ssrc, const int* __restrict__ sdst, float* __restrict__ ex, int e){
  int i = blockIdx.x * 256 + threadIdx.x;
  if (i >= e) return;
  int s = ssrc[i], d = sdst[i];
  if constexpr (H == 4){
    float4 a = *reinterpret_cast<const float4*>(&el[s * 4]);
    float4 b = *reinterpret_cast<const float4*>(&er[d * 4]);
    float4 o;
    o.x = expf(leakyf(a.x + b.x));
    o.y = expf(leakyf(a.y + b.y));
    o.z = expf(leakyf(a.z + b.z));
    o.w = expf(leakyf(a.w + b.w));
    *reinterpret_cast<float4*>(&ex[(size_t)i * 4]) = o;
  } else {
    const float* ap = &el[s * 6];
    const float* bp = &er[d * 6];
    float2 a0 = *reinterpret_cast<const float2*>(ap);
    float2 a1 = *reinterpret_cast<const float2*>(ap + 2);
    float2 a2 = *reinterpret_cast<const float2*>(ap + 4);
    float2 b0 = *reinterpret_cast<const float2*>(bp);
    float2 b1 = *reinterpret_cast<const float2*>(bp + 2);
    float2 b2 = *reinterpret_cast<const float2*>(bp + 4);
    float2 o0, o1, o2;
    o0.x = expf(leakyf(a0.x + b0.x)); o0.y = expf(leakyf(a0.y + b0.y));
    o1.x = expf(leakyf(a1.x + b1.x)); o1.y = expf(leakyf(a1.y + b1.y));
    o2.x = expf(leakyf(a2.x + b2.x)); o2.y = expf(leakyf(a2.y + b2.y));
    float* op = &ex[(size_t)i * 6];
    *reinterpret_cast<float2*>(op)     = o0;
    *reinterpret_cast<float2*>(op + 2) = o1;
    *reinterpret_cast<float2*>(op + 4) = o2;
  }
}

// ---------------- layer 0 fused: gather-aggregate + LDS contraction (node-pair remap) ----------------
__global__ __launch_bounds__(1024) void agg_l0_kernel(const float* __restrict__ embed,
    const float* __restrict__ W0, const float* __restrict__ ex,
    const int* __restrict__ row, const int* __restrict__ ssrc, float* __restrict__ h1){
  __shared__ float W0s[64 * 128];   // 32 KB
  __shared__ float gd[16][256];     // 16 KB
  int w = threadIdx.x >> 6, lane = threadIdx.x & 63;
  for (int v = threadIdx.x; v < 2048; v += 1024)
    *reinterpret_cast<float4*>(&W0s[v << 2]) = *reinterpret_cast<const float4*>(&W0[(size_t)v << 2]);
  int n = blockIdx.x * 16 + w;   // 50000 = 3125*16
  int beg = __builtin_amdgcn_readfirstlane(row[n]);
  int end = __builtin_amdgcn_readfirstlane(row[n + 1]);
  // pass 1: denominators
  float t0 = 0.f, t1 = 0.f, t2 = 0.f, t3 = 0.f;
  for (int i = beg + lane; i < end; i += 64){
    float4 e = *reinterpret_cast<const float4*>(&ex[(size_t)i * 4]);
    t0 += e.x; t1 += e.y; t2 += e.z; t3 += e.w;
  }
  #pragma unroll
  for (int o = 32; o; o >>= 1){
    t0 += __shfl_xor(t0, o, 64); t1 += __shfl_xor(t1, o, 64);
    t2 += __shfl_xor(t2, o, 64); t3 += __shfl_xor(t3, o, 64);
  }
  float i0 = t0 > 0.f ? 1.f / t0 : 0.f, i1 = t1 > 0.f ? 1.f / t1 : 0.f;
  float i2 = t2 > 0.f ? 1.f / t2 : 0.f, i3 = t3 > 0.f ? 1.f / t3 : 0.f;
  // pass 2: 8 outstanding gathers
  float g0 = 0.f, g1 = 0.f, g2 = 0.f, g3 = 0.f;
  int i = beg;
  for (; i + 8 <= end; i += 8){
    float v[8]; float4 e[8];
    #pragma unroll
    for (int u = 0; u < 8; ++u){
      int s = ssrc[i + u];
      v[u] = embed[(size_t)s * 64 + lane];
      e[u] = *reinterpret_cast<const float4*>(&ex[(size_t)(i + u) * 4]);
    }
    #pragma unroll
    for (int u = 0; u < 8; ++u){
      g0 += e[u].x * v[u]; g1 += e[u].y * v[u];
      g2 += e[u].z * v[u]; g3 += e[u].w * v[u];
    }
  }
  for (; i < end; ++i){
    int s = ssrc[i];
    float ev = embed[(size_t)s * 64 + lane];
    float4 e = *reinterpret_cast<const float4*>(&ex[(size_t)i * 4]);
    g0 += e.x * ev; g1 += e.y * ev; g2 += e.z * ev; g3 += e.w * ev;
  }
  gd[w][lane] = g0 * i0; gd[w][64 + lane] = g1 * i1;
  gd[w][128 + lane] = g2 * i2; gd[w][192 + lane] = g3 * i3;
  __syncthreads();
  // contraction: thread = (channel c, node-pair q); W0s scalar read once per 2 nodes
  int c = threadIdx.x & 127, q = threadIdx.x >> 7;   // q in [0,8)
  int h = c >> 5;
  const float* gp0 = &gd[2 * q][h * 64];
  const float* gp1 = &gd[2 * q + 1][h * 64];
  float o0 = 0.f, o1 = 0.f;
  #pragma unroll 8
  for (int k = 0; k < 64; ++k){
    float wv = W0s[(k << 7) + c];
    o0 += gp0[k] * wv;
    o1 += gp1[k] * wv;
  }
  int nb = blockIdx.x * 16;
  h1[(size_t)(nb + 2 * q) * 128 + c]     = eluf(o0);
  h1[(size_t)(nb + 2 * q + 1) * 128 + c] = eluf(o1);
}

// ---------------- layer 1 aggregation: wave per node, 8x unroll ----------------
__global__ __launch_bounds__(256) void agg32_kernel(const float* __restrict__ feat,
    const float* __restrict__ ex, const int* __restrict__ row, const int* __restrict__ ssrc,
    const float* __restrict__ resid, float* __restrict__ hout){
  int n = blockIdx.x * 4 + (threadIdx.x >> 6);
  if (n >= NNODES) return;
  int lane = threadIdx.x & 63, half = lane >> 5;
  int beg = __builtin_amdgcn_readfirstlane(row[n]);
  int end = __builtin_amdgcn_readfirstlane(row[n + 1]);
  float t0 = 0.f, t1 = 0.f, t2 = 0.f, t3 = 0.f;
  for (int i = beg + lane; i < end; i += 64){
    float4 e = *reinterpret_cast<const float4*>(&ex[(size_t)i * 4]);
    t0 += e.x; t1 += e.y; t2 += e.z; t3 += e.w;
  }
  #pragma unroll
  for (int o = 32; o; o >>= 1){
    t0 += __shfl_xor(t0, o, 64); t1 += __shfl_xor(t1, o, 64);
    t2 += __shfl_xor(t2, o, 64); t3 += __shfl_xor(t3, o, 64);
  }
  float invA = half ? (t1 > 0.f ? 1.f / t1 : 0.f) : (t0 > 0.f ? 1.f / t0 : 0.f);
  float invB = half ? (t3 > 0.f ? 1.f / t3 : 0.f) : (t2 > 0.f ? 1.f / t2 : 0.f);
  float acc0 = 0.f, acc1 = 0.f;
  int i = beg;
  for (; i + 8 <= end; i += 8){
    float a[8], b[8], eA[8], eB[8];
    #pragma unroll
    for (int u = 0; u < 8; ++u){
      int s = ssrc[i + u];
      const float* fr = feat + (size_t)s * 128;
      a[u] = fr[lane]; b[u] = fr[64 + lane];
      eA[u] = ex[(size_t)(i + u) * 4 + half];
      eB[u] = ex[(size_t)(i + u) * 4 + 2 + half];
    }
    #pragma unroll
    for (int u = 0; u < 8; ++u){ acc0 += eA[u] * a[u]; acc1 += eB[u] * b[u]; }
  }
  for (; i < end; ++i){
    int s = ssrc[i];
    const float* fr = feat + (size_t)s * 128;
    acc0 += ex[(size_t)i * 4 + half] * fr[lane];
    acc1 += ex[(size_t)i * 4 + 2 + half] * fr[64 + lane];
  }
  float v0 = acc0 * invA, v1 = acc1 * invB;
  size_t o0 = (size_t)n * 128 + lane;
  v0 += resid[o0]; v1 += resid[o0 + 64];
  hout[o0]      = eluf(v0);
  hout[o0 + 64] = eluf(v1);
}

// ---------------- layer 2 aggregation in h2-space, 8x unroll ----------------
__global__ __launch_bounds__(256) void agg_l2_kernel(const float* __restrict__ h2,
    const float* __restrict__ ex, const int* __restrict__ row, const int* __restrict__ ssrc,
    float* __restrict__ gs, int node_off, int node_cnt){
  int rel = blockIdx.x * 4 + (threadIdx.x >> 6);
  if (rel >= node_cnt) return;
  int n = node_off + rel;
  int lane = threadIdx.x & 63;
  int beg = __builtin_amdgcn_readfirstlane(row[n]);
  int end = __builtin_amdgcn_readfirstlane(row[n + 1]);
  float t[6] = {};
  for (int i = beg + lane; i < end; i += 64){
    const float* e = &ex[(size_t)i * 6];
    float2 a = *reinterpret_cast<const float2*>(e);
    float2 b = *reinterpret_cast<const float2*>(e + 2);
    float2 c = *reinterpret_cast<const float2*>(e + 4);
    t[0] += a.x; t[1] += a.y; t[2] += b.x; t[3] += b.y; t[4] += c.x; t[5] += c.y;
  }
  #pragma unroll
  for (int o = 32; o; o >>= 1){
    #pragma unroll
    for (int h = 0; h < 6; ++h) t[h] += __shfl_xor(t[h], o, 64);
  }
  float inv[6];
  #pragma unroll
  for (int h = 0; h < 6; ++h) inv[h] = t[h] > 0.f ? 1.f / (6.f * t[h]) : 0.f;
  float ga[6] = {}, gb[6] = {};
  int i = beg;
  for (; i + 8 <= end; i += 8){
    float v0[8], v1[8];
    float2 ea[8], eb[8], ec[8];
    #pragma unroll
    for (int u = 0; u < 8; ++u){
      int s = ssrc[i + u];
      const float* hr = h2 + (size_t)s * 128;
      v0[u] = hr[lane]; v1[u] = hr[64 + lane];
      const float* e = &ex[(size_t)(i + u) * 6];
      ea[u] = *reinterpret_cast<const float2*>(e);
      eb[u] = *reinterpret_cast<const float2*>(e + 2);
      ec[u] = *reinterpret_cast<const float2*>(e + 4);
    }
    #pragma unroll
    for (int u = 0; u < 8; ++u){
      ga[0] += ea[u].x * v0[u]; gb[0] += ea[u].x * v1[u];
      ga[1] += ea[u].y * v0[u]; gb[1] += ea[u].y * v1[u];
      ga[2] += eb[u].x * v0[u]; gb[2] += eb[u].x * v1[u];
      ga[3] += eb[u].y * v0[u]; gb[3] += eb[u].y * v1[u];
      ga[4] += ec[u].x * v0[u]; gb[4] += ec[u].x * v1[u];
      ga[5] += ec[u].y * v0[u]; gb[5] += ec[u].y * v1[u];
    }
  }
  for (; i < end; ++i){
    int s = ssrc[i];
    const float* hr = h2 + (size_t)s * 128;
    float v0 = hr[lane], v1 = hr[64 + lane];
    const float* e = &ex[(size_t)i * 6];
    float2 a = *reinterpret_cast<const float2*>(e);
    float2 b = *reinterpret_cast<const float2*>(e + 2);
    float2 c = *reinterpret_cast<const float2*>(e + 4);
    ga[0] += a.x * v0; gb[0] += a.x * v1;
    ga[1] += a.y * v0; gb[1] += a.y * v1;
    ga[2] += b.x * v0; gb[2] += b.x * v1;
    ga[3] += b.y * v0; gb[3] += b.y * v1;
    ga[4] += c.x * v0; gb[4] += c.x * v1;
    ga[5] += c.y * v0; gb[5] += c.y * v1;
  }
  float* gr = gs + (size_t)rel * 768;
  #pragma unroll
  for (int h = 0; h < 6; ++h){
    gr[h * 128 + lane]      = ga[h] * inv[h];
    gr[h * 128 + 64 + lane] = gb[h] * inv[h];
  }
}

// ---------------- launch ----------------
extern "C" void kernel_launch(void* const* d_in, const int* in_sizes, int n_in,
                              void* d_out, int out_size, void* d_ws, size_t ws_size,
                              hipStream_t stream){
  const int*   src   = (const int*)d_in[0];
  const int*   dst   = (const int*)d_in[1];
  const float* embed = (const float*)d_in[2];
  const float* W0    = (const float*)d_in[3];
  const float* al0   = (const float*)d_in[4];
  const float* ar0   = (const float*)d_in[5];
  const float* W1    = (const float*)d_in[6];
  const float* al1   = (const float*)d_in[7];
  const float* ar1   = (const float*)d_in[8];
  const float* W2    = (const float*)d_in[9];
  const float* al2   = (const float*)d_in[10];
  const float* ar2   = (const float*)d_in[11];
  const float* Wres  = (const float*)d_in[12];
  float* out = (float*)d_out;

  char* p = (char*)d_ws;
  auto alloc = [&](size_t bytes) -> char* {
    char* r = p; p += (bytes + 255) & ~size_t(255); return r;
  };
  float* big  = (float*)alloc((size_t)25000 * 768 * 4);   // feat1 then gs halves
  float* h1   = (float*)alloc((size_t)NNODES * 128 * 4);
  float* h2   = (float*)alloc((size_t)NNODES * 128 * 4);
  float* el   = (float*)alloc((size_t)NNODES * 6 * 4);
  float* er   = (float*)alloc((size_t)NNODES * 6 * 4);
  float* ex   = (float*)alloc((size_t)NEDGES * 6 * 4);
  float* wm   = (float*)alloc(128 * 64 * 4);
  float* W2r  = (float*)alloc(768 * 64 * 4);
  float* wl0  = (float*)alloc(4 * 64 * 4);
  float* wr0  = (float*)alloc(4 * 64 * 4);
  float* wl2  = (float*)alloc(6 * 128 * 4);
  float* wr2  = (float*)alloc(6 * 128 * 4);
  int* row    = (int*)alloc((NNODES + 1) * 4);
  int* cur    = (int*)alloc(NNODES * 4);
  int* deg    = (int*)alloc(NNODES * 4);
  int* pre    = (int*)alloc(NNODES * 4);
  int* bsum   = (int*)alloc(256 * 4);
  int* ssrc   = (int*)alloc(NEDGES * 4);
  int* sdst   = (int*)alloc(NEDGES * 4);

  const int NB = (NNODES + 255) / 256;

  // CSR by dst
  hipMemsetAsync(deg, 0, NNODES * 4, stream);
  hist_kernel<<<(NEDGES + 255) / 256, 256, 0, stream>>>(dst, deg, NEDGES);
  scan1_kernel<<<NB, 256, 0, stream>>>(deg, pre, bsum, NNODES);
  scan2_kernel<<<1, 256, 0, stream>>>(bsum, NB);
  scan3_kernel<<<NB + 1, 256, 0, stream>>>(pre, bsum, row, cur, NNODES, NEDGES);
  scatter_kernel<<<(NEDGES + 255) / 256, 256, 0, stream>>>(src, dst, cur, ssrc, sdst, NEDGES);

  // weight prep (single combined dispatch)
  prep_kernel<<<228, 256, 0, stream>>>(W0, al0, ar0, W2, al2, ar2, Wres,
                                       wl0, wr0, wl2, wr2, wm, W2r);

  const int GX = (NNODES + 63) / 64;
  const int GE = (NEDGES + 255) / 256;
  const int GN = (NNODES + 3) / 4;
  const int GNn = (NNODES + 255) / 256;

  // ---- layer 0
  elrn_kernel<4, 64><<<GNn, 256, 0, stream>>>(embed, wl0, wr0, el, er);
  ex_kernel<4><<<GE, 256, 0, stream>>>(el, er, ssrc, sdst, ex, NEDGES);
  agg_l0_kernel<<<NNODES / 16, 1024, 0, stream>>>(embed, W0, ex, row, ssrc, h1);

  // ---- layer 1
  gemm_kernel<128, false><<<dim3(GX, 2), 256, 0, stream>>>(h1, W1, big, NNODES, 128);
  elr1_kernel<<<GNn, 256, 0, stream>>>(big, al1, ar1, el, er);
  ex_kernel<4><<<GE, 256, 0, stream>>>(el, er, ssrc, sdst, ex, NEDGES);
  agg32_kernel<<<GN, 256, 0, stream>>>(big, ex, row, ssrc, h1, h2);

  // ---- layer 2
  elrn_kernel<6, 128><<<GNn, 256, 0, stream>>>(h2, wl2, wr2, el, er);
  ex_kernel<6><<<GE, 256, 0, stream>>>(el, er, ssrc, sdst, ex, NEDGES);
  gemm_kernel<128, false><<<dim3(GX, 1), 256, 0, stream>>>(h2, wm, out, NNODES, 64);
  const int HALF = 25000;
  for (int half = 0; half < 2; ++half){
    int off = half * HALF;
    agg_l2_kernel<<<(HALF + 3) / 4, 256, 0, stream>>>(h2, ex, row, ssrc, big, off, HALF);
    gemm32_kernel<768, true><<<dim3((HALF + 31) / 32, 1), 256, 0, stream>>>(
        big, W2r, out + (size_t)off * 64, HALF, 64);
  }
}

// Round 13
// 547.762 us; speedup vs baseline: 1.0279x; 1.0279x over previous
//
#include <hip/hip_runtime.h>
#include <hip/hip_bf16.h>
#include <cstdint>

#define NNODES 50000
#define NEDGES 800000
constexpr float SLOPE = 0.2f;

__device__ __forceinline__ float leakyf(float x){ return x > 0.f ? x : SLOPE * x; }
__device__ __forceinline__ float eluf(float x){ return x > 0.f ? x : expm1f(x); }

// ---------------- CSR build (by dst) ----------------
__global__ void hist_kernel(const int* __restrict__ dst, int* __restrict__ deg, int e){
  int i = blockIdx.x * 256 + threadIdx.x;
  if (i < e) atomicAdd(&deg[dst[i]], 1);
}

__global__ __launch_bounds__(256) void scan1_kernel(const int* __restrict__ deg,
    int* __restrict__ pre, int* __restrict__ bsum, int n){
  __shared__ int s[256];
  int t = threadIdx.x;
  int i = blockIdx.x * 256 + t;
  int v = (i < n) ? deg[i] : 0;
  s[t] = v;
  __syncthreads();
  #pragma unroll
  for (int off = 1; off < 256; off <<= 1){
    int x = (t >= off) ? s[t - off] : 0;
    __syncthreads();
    s[t] += x;
    __syncthreads();
  }
  if (i < n) pre[i] = s[t] - v;
  if (t == 255) bsum[blockIdx.x] = s[255];
}

__global__ __launch_bounds__(256) void scan2_kernel(int* __restrict__ bsum, int nb){
  __shared__ int s[256];
  int t = threadIdx.x;
  int v = (t < nb) ? bsum[t] : 0;
  s[t] = v;
  __syncthreads();
  #pragma unroll
  for (int off = 1; off < 256; off <<= 1){
    int x = (t >= off) ? s[t - off] : 0;
    __syncthreads();
    s[t] += x;
    __syncthreads();
  }
  if (t < nb) bsum[t] = s[t] - v;
}

__global__ __launch_bounds__(256) void scan3_kernel(const int* __restrict__ pre,
    const int* __restrict__ bsum, int* __restrict__ row, int* __restrict__ cur,
    int n, int etot){
  int i = blockIdx.x * 256 + threadIdx.x;
  if (i < n){
    int r = pre[i] + bsum[i >> 8];
    row[i] = r; cur[i] = r;
  }
  if (i == n) row[n] = etot;
}

__global__ void scatter_kernel(const int* __restrict__ src, const int* __restrict__ dst,
    int* __restrict__ cur, int* __restrict__ ssrc, int* __restrict__ sdst, int e){
  int i = blockIdx.x * 256 + threadIdx.x;
  if (i < e){
    int d = dst[i];
    int pos = atomicAdd(&cur[d], 1);
    ssrc[pos] = src[i];
    sdst[pos] = d;
  }
}

// ---------------- f32 tiled GEMM 64x64 (A-tile transposed in LDS: b128 fragment reads) ----------------
template<int K, bool ACC>
__global__ __launch_bounds__(256) void gemm_kernel(const float* __restrict__ A,
    const float* __restrict__ B, float* __restrict__ C, int n_rows, int n_cols){
  __shared__ float Ast[64][68];   // transposed: Ast[k][r]
  __shared__ float Bs[64][64];
  int tx = threadIdx.x & 15, ty = threadIdx.x >> 4;
  int row0 = blockIdx.x * 64, col0 = blockIdx.y * 64;
  float acc[4][4] = {};
  for (int k0 = 0; k0 < K; k0 += 64){
    for (int v = threadIdx.x; v < 1024; v += 256){
      int r = v >> 4, c = (v & 15) << 2;
      float4 val = make_float4(0.f, 0.f, 0.f, 0.f);
      int gr = row0 + r;
      if (gr < n_rows) val = *reinterpret_cast<const float4*>(&A[(size_t)gr * K + k0 + c]);
      Ast[c + 0][r] = val.x;
      Ast[c + 1][r] = val.y;
      Ast[c + 2][r] = val.z;
      Ast[c + 3][r] = val.w;
    }
    for (int v = threadIdx.x; v < 1024; v += 256){
      int r = v >> 4, c = (v & 15) << 2;
      *reinterpret_cast<float4*>(&Bs[r][c]) =
        *reinterpret_cast<const float4*>(&B[(size_t)(k0 + r) * n_cols + col0 + c]);
    }
    __syncthreads();
    #pragma unroll 8
    for (int k = 0; k < 64; ++k){
      float4 av = *reinterpret_cast<const float4*>(&Ast[k][ty << 2]);
      float4 bv = *reinterpret_cast<const float4*>(&Bs[k][tx << 2]);
      float a[4] = {av.x, av.y, av.z, av.w};
      float b[4] = {bv.x, bv.y, bv.z, bv.w};
      #pragma unroll
      for (int i = 0; i < 4; ++i)
        #pragma unroll
        for (int j = 0; j < 4; ++j)
          acc[i][j] += a[i] * b[j];
    }
    __syncthreads();
  }
  #pragma unroll
  for (int i = 0; i < 4; ++i){
    int gr = row0 + ty * 4 + i;
    if (gr < n_rows){
      float* cp = &C[(size_t)gr * n_cols + col0 + tx * 4];
      float4 v = make_float4(acc[i][0], acc[i][1], acc[i][2], acc[i][3]);
      if constexpr (ACC){
        float4 o = *reinterpret_cast<const float4*>(cp);
        v.x += o.x; v.y += o.y; v.z += o.z; v.w += o.w;
      }
      *reinterpret_cast<float4*>(cp) = v;
    }
  }
}

// ---------------- combined weight prep: wvec0 | wvec2 | wresmean | w2r in one dispatch ----------------
__global__ __launch_bounds__(256) void prep_kernel(const float* __restrict__ W0,
    const float* __restrict__ al0, const float* __restrict__ ar0,
    const float* __restrict__ W2, const float* __restrict__ al2, const float* __restrict__ ar2,
    const float* __restrict__ Wres,
    float* __restrict__ wl0, float* __restrict__ wr0,
    float* __restrict__ wl2, float* __restrict__ wr2,
    float* __restrict__ wm, float* __restrict__ W2r){
  int b = blockIdx.x, t = threadIdx.x;
  if (b == 0){
    int h = t >> 6, k = t & 63;
    const float* wrow = W0 + (size_t)k * 128 + h * 32;
    const float* a = al0 + h * 32;
    const float* r = ar0 + h * 32;
    float sl = 0.f, sr = 0.f;
    #pragma unroll
    for (int d = 0; d < 32; ++d){ float wv = wrow[d]; sl += wv * a[d]; sr += wv * r[d]; }
    wl0[t] = sl; wr0[t] = sr;
  } else if (b < 4){
    int idx = (b - 1) * 256 + t;
    int h = idx / 128, k = idx - h * 128;
    const float* wrow = W2 + (size_t)k * 384 + h * 64;
    const float* a = al2 + h * 64;
    const float* r = ar2 + h * 64;
    float sl = 0.f, sr = 0.f;
    #pragma unroll
    for (int d = 0; d < 64; ++d){ float wv = wrow[d]; sl += wv * a[d]; sr += wv * r[d]; }
    wl2[idx] = sl; wr2[idx] = sr;
  } else if (b < 36){
    int i = (b - 4) * 256 + t;
    int k = i >> 6, c = i & 63;
    float s = 0.f;
    #pragma unroll
    for (int h = 0; h < 6; ++h) s += Wres[k * 384 + h * 64 + c];
    wm[i] = s * (1.f / 6.f);
  } else {
    int i = (b - 36) * 256 + t;
    int hk = i >> 6, c = i & 63;
    int h = hk >> 7, k = hk & 127;
    W2r[i] = W2[(size_t)k * 384 + h * 64 + c];
  }
}

// ---------------- node-parallel el/er from raw features ----------------
template<int H, int K>
__global__ __launch_bounds__(256) void elrn_kernel(const float* __restrict__ x,
    const float* __restrict__ wl, const float* __restrict__ wr,
    float* __restrict__ el, float* __restrict__ er){
  __shared__ float wls[H * K], wrs[H * K];
  for (int v = threadIdx.x; v < H * K; v += 256){ wls[v] = wl[v]; wrs[v] = wr[v]; }
  __syncthreads();
  int n = blockIdx.x * 256 + threadIdx.x;
  if (n >= NNODES) return;
  const float* xr = x + (size_t)n * K;
  float accl[H] = {}, accr[H] = {};
  for (int k = 0; k < K; k += 4){
    float4 xv = *reinterpret_cast<const float4*>(xr + k);
    #pragma unroll
    for (int h = 0; h < H; ++h){
      const float* a = &wls[h * K + k];
      const float* b = &wrs[h * K + k];
      accl[h] += xv.x * a[0] + xv.y * a[1] + xv.z * a[2] + xv.w * a[3];
      accr[h] += xv.x * b[0] + xv.y * b[1] + xv.z * b[2] + xv.w * b[3];
    }
  }
  #pragma unroll
  for (int h = 0; h < H; ++h){ el[n * H + h] = accl[h]; er[n * H + h] = accr[h]; }
}

// ---------------- node-parallel el/er for layer 1 ----------------
__global__ __launch_bounds__(256) void elr1_kernel(const float* __restrict__ feat,
    const float* __restrict__ al, const float* __restrict__ ar,
    float* __restrict__ el, float* __restrict__ er){
  __shared__ float als[128], ars[128];
  if (threadIdx.x < 128){ als[threadIdx.x] = al[threadIdx.x]; ars[threadIdx.x] = ar[threadIdx.x]; }
  __syncthreads();
  int n = blockIdx.x * 256 + threadIdx.x;
  if (n >= NNODES) return;
  const float* f = feat + (size_t)n * 128;
  float el4[4], er4[4];
  #pragma unroll
  for (int h = 0; h < 4; ++h){
    float sl = 0.f, sr = 0.f;
    #pragma unroll
    for (int d = 0; d < 32; d += 4){
      float4 fv = *reinterpret_cast<const float4*>(f + h * 32 + d);
      const float* a = &als[h * 32 + d];
      const float* b = &ars[h * 32 + d];
      sl += fv.x * a[0] + fv.y * a[1] + fv.z * a[2] + fv.w * a[3];
      sr += fv.x * b[0] + fv.y * b[1] + fv.z * b[2] + fv.w * b[3];
    }
    el4[h] = sl; er4[h] = sr;
  }
  *reinterpret_cast<float4*>(&el[n * 4]) = make_float4(el4[0], el4[1], el4[2], el4[3]);
  *reinterpret_cast<float4*>(&er[n * 4]) = make_float4(er4[0], er4[1], er4[2], er4[3]);
}

// ---------------- ex = exp(leaky(el[src]+er[dst])) ----------------
template<int H>
__global__ void ex_kernel(const float* __restrict__ el, const float* __restrict__ er,
    const int* __restrict__ ssrc, const int* __restrict__ sdst, float* __restrict__ ex, int e){
  int i = blockIdx.x * 256 + threadIdx.x;
  if (i >= e) return;
  int s = ssrc[i], d = sdst[i];
  if constexpr (H == 4){
    float4 a = *reinterpret_cast<const float4*>(&el[s * 4]);
    float4 b = *reinterpret_cast<const float4*>(&er[d * 4]);
    float4 o;
    o.x = expf(leakyf(a.x + b.x));
    o.y = expf(leakyf(a.y + b.y));
    o.z = expf(leakyf(a.z + b.z));
    o.w = expf(leakyf(a.w + b.w));
    *reinterpret_cast<float4*>(&ex[(size_t)i * 4]) = o;
  } else {
    const float* ap = &el[s * 6];
    const float* bp = &er[d * 6];
    float2 a0 = *reinterpret_cast<const float2*>(ap);
    float2 a1 = *reinterpret_cast<const float2*>(ap + 2);
    float2 a2 = *reinterpret_cast<const float2*>(ap + 4);
    float2 b0 = *reinterpret_cast<const float2*>(bp);
    float2 b1 = *reinterpret_cast<const float2*>(bp + 2);
    float2 b2 = *reinterpret_cast<const float2*>(bp + 4);
    float2 o0, o1, o2;
    o0.x = expf(leakyf(a0.x + b0.x)); o0.y = expf(leakyf(a0.y + b0.y));
    o1.x = expf(leakyf(a1.x + b1.x)); o1.y = expf(leakyf(a1.y + b1.y));
    o2.x = expf(leakyf(a2.x + b2.x)); o2.y = expf(leakyf(a2.y + b2.y));
    float* op = &ex[(size_t)i * 6];
    *reinterpret_cast<float2*>(op)     = o0;
    *reinterpret_cast<float2*>(op + 2) = o1;
    *reinterpret_cast<float2*>(op + 4) = o2;
  }
}

// ---------------- layer 0 fused: gather-aggregate + LDS contraction (node-pair remap) ----------------
__global__ __launch_bounds__(1024) void agg_l0_kernel(const float* __restrict__ embed,
    const float* __restrict__ W0, const float* __restrict__ ex,
    const int* __restrict__ row, const int* __restrict__ ssrc, float* __restrict__ h1){
  __shared__ float W0s[64 * 128];   // 32 KB
  __shared__ float gd[16][256];     // 16 KB
  int w = threadIdx.x >> 6, lane = threadIdx.x & 63;
  for (int v = threadIdx.x; v < 2048; v += 1024)
    *reinterpret_cast<float4*>(&W0s[v << 2]) = *reinterpret_cast<const float4*>(&W0[(size_t)v << 2]);
  int n = blockIdx.x * 16 + w;   // 50000 = 3125*16
  int beg = __builtin_amdgcn_readfirstlane(row[n]);
  int end = __builtin_amdgcn_readfirstlane(row[n + 1]);
  // pass 1: denominators
  float t0 = 0.f, t1 = 0.f, t2 = 0.f, t3 = 0.f;
  for (int i = beg + lane; i < end; i += 64){
    float4 e = *reinterpret_cast<const float4*>(&ex[(size_t)i * 4]);
    t0 += e.x; t1 += e.y; t2 += e.z; t3 += e.w;
  }
  #pragma unroll
  for (int o = 32; o; o >>= 1){
    t0 += __shfl_xor(t0, o, 64); t1 += __shfl_xor(t1, o, 64);
    t2 += __shfl_xor(t2, o, 64); t3 += __shfl_xor(t3, o, 64);
  }
  float i0 = t0 > 0.f ? 1.f / t0 : 0.f, i1 = t1 > 0.f ? 1.f / t1 : 0.f;
  float i2 = t2 > 0.f ? 1.f / t2 : 0.f, i3 = t3 > 0.f ? 1.f / t3 : 0.f;
  // pass 2: 8 outstanding gathers
  float g0 = 0.f, g1 = 0.f, g2 = 0.f, g3 = 0.f;
  int i = beg;
  for (; i + 8 <= end; i += 8){
    float v[8]; float4 e[8];
    #pragma unroll
    for (int u = 0; u < 8; ++u){
      int s = ssrc[i + u];
      v[u] = embed[(size_t)s * 64 + lane];
      e[u] = *reinterpret_cast<const float4*>(&ex[(size_t)(i + u) * 4]);
    }
    #pragma unroll
    for (int u = 0; u < 8; ++u){
      g0 += e[u].x * v[u]; g1 += e[u].y * v[u];
      g2 += e[u].z * v[u]; g3 += e[u].w * v[u];
    }
  }
  for (; i < end; ++i){
    int s = ssrc[i];
    float ev = embed[(size_t)s * 64 + lane];
    float4 e = *reinterpret_cast<const float4*>(&ex[(size_t)i * 4]);
    g0 += e.x * ev; g1 += e.y * ev; g2 += e.z * ev; g3 += e.w * ev;
  }
  gd[w][lane] = g0 * i0; gd[w][64 + lane] = g1 * i1;
  gd[w][128 + lane] = g2 * i2; gd[w][192 + lane] = g3 * i3;
  __syncthreads();
  // contraction: thread = (channel c, node-pair q); W0s scalar read once per 2 nodes
  int c = threadIdx.x & 127, q = threadIdx.x >> 7;   // q in [0,8)
  int h = c >> 5;
  const float* gp0 = &gd[2 * q][h * 64];
  const float* gp1 = &gd[2 * q + 1][h * 64];
  float o0 = 0.f, o1 = 0.f;
  #pragma unroll 8
  for (int k = 0; k < 64; ++k){
    float wv = W0s[(k << 7) + c];
    o0 += gp0[k] * wv;
    o1 += gp1[k] * wv;
  }
  int nb = blockIdx.x * 16;
  h1[(size_t)(nb + 2 * q) * 128 + c]     = eluf(o0);
  h1[(size_t)(nb + 2 * q + 1) * 128 + c] = eluf(o1);
}

// ---------------- layer 1 aggregation: wave per node, 8x unroll ----------------
__global__ __launch_bounds__(256) void agg32_kernel(const float* __restrict__ feat,
    const float* __restrict__ ex, const int* __restrict__ row, const int* __restrict__ ssrc,
    const float* __restrict__ resid, float* __restrict__ hout){
  int n = blockIdx.x * 4 + (threadIdx.x >> 6);
  if (n >= NNODES) return;
  int lane = threadIdx.x & 63, half = lane >> 5;
  int beg = __builtin_amdgcn_readfirstlane(row[n]);
  int end = __builtin_amdgcn_readfirstlane(row[n + 1]);
  float t0 = 0.f, t1 = 0.f, t2 = 0.f, t3 = 0.f;
  for (int i = beg + lane; i < end; i += 64){
    float4 e = *reinterpret_cast<const float4*>(&ex[(size_t)i * 4]);
    t0 += e.x; t1 += e.y; t2 += e.z; t3 += e.w;
  }
  #pragma unroll
  for (int o = 32; o; o >>= 1){
    t0 += __shfl_xor(t0, o, 64); t1 += __shfl_xor(t1, o, 64);
    t2 += __shfl_xor(t2, o, 64); t3 += __shfl_xor(t3, o, 64);
  }
  float invA = half ? (t1 > 0.f ? 1.f / t1 : 0.f) : (t0 > 0.f ? 1.f / t0 : 0.f);
  float invB = half ? (t3 > 0.f ? 1.f / t3 : 0.f) : (t2 > 0.f ? 1.f / t2 : 0.f);
  float acc0 = 0.f, acc1 = 0.f;
  int i = beg;
  for (; i + 8 <= end; i += 8){
    float a[8], b[8], eA[8], eB[8];
    #pragma unroll
    for (int u = 0; u < 8; ++u){
      int s = ssrc[i + u];
      const float* fr = feat + (size_t)s * 128;
      a[u] = fr[lane]; b[u] = fr[64 + lane];
      eA[u] = ex[(size_t)(i + u) * 4 + half];
      eB[u] = ex[(size_t)(i + u) * 4 + 2 + half];
    }
    #pragma unroll
    for (int u = 0; u < 8; ++u){ acc0 += eA[u] * a[u]; acc1 += eB[u] * b[u]; }
  }
  for (; i < end; ++i){
    int s = ssrc[i];
    const float* fr = feat + (size_t)s * 128;
    acc0 += ex[(size_t)i * 4 + half] * fr[lane];
    acc1 += ex[(size_t)i * 4 + 2 + half] * fr[64 + lane];
  }
  float v0 = acc0 * invA, v1 = acc1 * invB;
  size_t o0 = (size_t)n * 128 + lane;
  v0 += resid[o0]; v1 += resid[o0 + 64];
  hout[o0]      = eluf(v0);
  hout[o0 + 64] = eluf(v1);
}

// ---------------- layer 2 aggregation in h2-space, 8x unroll ----------------
__global__ __launch_bounds__(256) void agg_l2_kernel(const float* __restrict__ h2,
    const float* __restrict__ ex, const int* __restrict__ row, const int* __restrict__ ssrc,
    float* __restrict__ gs, int node_off, int node_cnt){
  int rel = blockIdx.x * 4 + (threadIdx.x >> 6);
  if (rel >= node_cnt) return;
  int n = node_off + rel;
  int lane = threadIdx.x & 63;
  int beg = __builtin_amdgcn_readfirstlane(row[n]);
  int end = __builtin_amdgcn_readfirstlane(row[n + 1]);
  float t[6] = {};
  for (int i = beg + lane; i < end; i += 64){
    const float* e = &ex[(size_t)i * 6];
    float2 a = *reinterpret_cast<const float2*>(e);
    float2 b = *reinterpret_cast<const float2*>(e + 2);
    float2 c = *reinterpret_cast<const float2*>(e + 4);
    t[0] += a.x; t[1] += a.y; t[2] += b.x; t[3] += b.y; t[4] += c.x; t[5] += c.y;
  }
  #pragma unroll
  for (int o = 32; o; o >>= 1){
    #pragma unroll
    for (int h = 0; h < 6; ++h) t[h] += __shfl_xor(t[h], o, 64);
  }
  float inv[6];
  #pragma unroll
  for (int h = 0; h < 6; ++h) inv[h] = t[h] > 0.f ? 1.f / (6.f * t[h]) : 0.f;
  float ga[6] = {}, gb[6] = {};
  int i = beg;
  for (; i + 8 <= end; i += 8){
    float v0[8], v1[8];
    float2 ea[8], eb[8], ec[8];
    #pragma unroll
    for (int u = 0; u < 8; ++u){
      int s = ssrc[i + u];
      const float* hr = h2 + (size_t)s * 128;
      v0[u] = hr[lane]; v1[u] = hr[64 + lane];
      const float* e = &ex[(size_t)(i + u) * 6];
      ea[u] = *reinterpret_cast<const float2*>(e);
      eb[u] = *reinterpret_cast<const float2*>(e + 2);
      ec[u] = *reinterpret_cast<const float2*>(e + 4);
    }
    #pragma unroll
    for (int u = 0; u < 8; ++u){
      ga[0] += ea[u].x * v0[u]; gb[0] += ea[u].x * v1[u];
      ga[1] += ea[u].y * v0[u]; gb[1] += ea[u].y * v1[u];
      ga[2] += eb[u].x * v0[u]; gb[2] += eb[u].x * v1[u];
      ga[3] += eb[u].y * v0[u]; gb[3] += eb[u].y * v1[u];
      ga[4] += ec[u].x * v0[u]; gb[4] += ec[u].x * v1[u];
      ga[5] += ec[u].y * v0[u]; gb[5] += ec[u].y * v1[u];
    }
  }
  for (; i < end; ++i){
    int s = ssrc[i];
    const float* hr = h2 + (size_t)s * 128;
    float v0 = hr[lane], v1 = hr[64 + lane];
    const float* e = &ex[(size_t)i * 6];
    float2 a = *reinterpret_cast<const float2*>(e);
    float2 b = *reinterpret_cast<const float2*>(e + 2);
    float2 c = *reinterpret_cast<const float2*>(e + 4);
    ga[0] += a.x * v0; gb[0] += a.x * v1;
    ga[1] += a.y * v0; gb[1] += a.y * v1;
    ga[2] += b.x * v0; gb[2] += b.x * v1;
    ga[3] += b.y * v0; gb[3] += b.y * v1;
    ga[4] += c.x * v0; gb[4] += c.x * v1;
    ga[5] += c.y * v0; gb[5] += c.y * v1;
  }
  float* gr = gs + (size_t)rel * 768;
  #pragma unroll
  for (int h = 0; h < 6; ++h){
    gr[h * 128 + lane]      = ga[h] * inv[h];
    gr[h * 128 + 64 + lane] = gb[h] * inv[h];
  }
}

// ---------------- launch ----------------
extern "C" void kernel_launch(void* const* d_in, const int* in_sizes, int n_in,
                              void* d_out, int out_size, void* d_ws, size_t ws_size,
                              hipStream_t stream){
  const int*   src   = (const int*)d_in[0];
  const int*   dst   = (const int*)d_in[1];
  const float* embed = (const float*)d_in[2];
  const float* W0    = (const float*)d_in[3];
  const float* al0   = (const float*)d_in[4];
  const float* ar0   = (const float*)d_in[5];
  const float* W1    = (const float*)d_in[6];
  const float* al1   = (const float*)d_in[7];
  const float* ar1   = (const float*)d_in[8];
  const float* W2    = (const float*)d_in[9];
  const float* al2   = (const float*)d_in[10];
  const float* ar2   = (const float*)d_in[11];
  const float* Wres  = (const float*)d_in[12];
  float* out = (float*)d_out;

  char* p = (char*)d_ws;
  auto alloc = [&](size_t bytes) -> char* {
    char* r = p; p += (bytes + 255) & ~size_t(255); return r;
  };
  float* big  = (float*)alloc((size_t)25000 * 768 * 4);   // feat1 then gs halves
  float* h1   = (float*)alloc((size_t)NNODES * 128 * 4);
  float* h2   = (float*)alloc((size_t)NNODES * 128 * 4);
  float* el   = (float*)alloc((size_t)NNODES * 6 * 4);
  float* er   = (float*)alloc((size_t)NNODES * 6 * 4);
  float* ex   = (float*)alloc((size_t)NEDGES * 6 * 4);
  float* wm   = (float*)alloc(128 * 64 * 4);
  float* W2r  = (float*)alloc(768 * 64 * 4);
  float* wl0  = (float*)alloc(4 * 64 * 4);
  float* wr0  = (float*)alloc(4 * 64 * 4);
  float* wl2  = (float*)alloc(6 * 128 * 4);
  float* wr2  = (float*)alloc(6 * 128 * 4);
  int* row    = (int*)alloc((NNODES + 1) * 4);
  int* cur    = (int*)alloc(NNODES * 4);
  int* deg    = (int*)alloc(NNODES * 4);
  int* pre    = (int*)alloc(NNODES * 4);
  int* bsum   = (int*)alloc(256 * 4);
  int* ssrc   = (int*)alloc(NEDGES * 4);
  int* sdst   = (int*)alloc(NEDGES * 4);

  const int NB = (NNODES + 255) / 256;

  // CSR by dst
  hipMemsetAsync(deg, 0, NNODES * 4, stream);
  hist_kernel<<<(NEDGES + 255) / 256, 256, 0, stream>>>(dst, deg, NEDGES);
  scan1_kernel<<<NB, 256, 0, stream>>>(deg, pre, bsum, NNODES);
  scan2_kernel<<<1, 256, 0, stream>>>(bsum, NB);
  scan3_kernel<<<NB + 1, 256, 0, stream>>>(pre, bsum, row, cur, NNODES, NEDGES);
  scatter_kernel<<<(NEDGES + 255) / 256, 256, 0, stream>>>(src, dst, cur, ssrc, sdst, NEDGES);

  // weight prep (single combined dispatch)
  prep_kernel<<<228, 256, 0, stream>>>(W0, al0, ar0, W2, al2, ar2, Wres,
                                       wl0, wr0, wl2, wr2, wm, W2r);

  const int GX = (NNODES + 63) / 64;
  const int GE = (NEDGES + 255) / 256;
  const int GN = (NNODES + 3) / 4;
  const int GNn = (NNODES + 255) / 256;

  // ---- layer 0
  elrn_kernel<4, 64><<<GNn, 256, 0, stream>>>(embed, wl0, wr0, el, er);
  ex_kernel<4><<<GE, 256, 0, stream>>>(el, er, ssrc, sdst, ex, NEDGES);
  agg_l0_kernel<<<NNODES / 16, 1024, 0, stream>>>(embed, W0, ex, row, ssrc, h1);

  // ---- layer 1
  gemm_kernel<128, false><<<dim3(GX, 2), 256, 0, stream>>>(h1, W1, big, NNODES, 128);
  elr1_kernel<<<GNn, 256, 0, stream>>>(big, al1, ar1, el, er);
  ex_kernel<4><<<GE, 256, 0, stream>>>(el, er, ssrc, sdst, ex, NEDGES);
  agg32_kernel<<<GN, 256, 0, stream>>>(big, ex, row, ssrc, h1, h2);

  // ---- layer 2
  elrn_kernel<6, 128><<<GNn, 256, 0, stream>>>(h2, wl2, wr2, el, er);
  ex_kernel<6><<<GE, 256, 0, stream>>>(el, er, ssrc, sdst, ex, NEDGES);
  gemm_kernel<128, false><<<dim3(GX, 1), 256, 0, stream>>>(h2, wm, out, NNODES, 64);
  const int HALF = 25000;
  for (int half = 0; half < 2; ++half){
    int off = half * HALF;
    agg_l2_kernel<<<(HALF + 3) / 4, 256, 0, stream>>>(h2, ex, row, ssrc, big, off, HALF);
    gemm_kernel<768, true><<<dim3((HALF + 63) / 64, 1), 256, 0, stream>>>(
        big, W2r, out + (size_t)off * 64, HALF, 64);
  }
}